// Round 5
// baseline (341.635 us; speedup 1.0000x reference)
//
#include <hip/hip_runtime.h>

#define N_B   262144
#define BM    64       // rows per block: hA = 64*296*2 = 37,888 B -> 4 blocks/CU
#define KAUG  288      // 256 (h) + 32 (x-augmentation, only 3 used)
#define LDA   296      // hA row stride in halves

typedef _Float16 f16x8  __attribute__((ext_vector_type(8)));
typedef _Float16 f16x4  __attribute__((ext_vector_type(4)));
typedef float    f32x16 __attribute__((ext_vector_type(16)));

// ---------------------------------------------------------------------------
// Precompute (68 blocks, ~5 us):
//   blocks 0..63 : (l = b>>4, row-group ng = b&15) -> Mt[l][16ng..16ng+16)[*]
//   blocks 64..67: W1t[n][k] = W1[k][n] transpose.
// ---------------------------------------------------------------------------
__global__ void fno_precompute(const float* __restrict__ W1,
                               const float* __restrict__ fw,
                               const float* __restrict__ lw,
                               _Float16* __restrict__ Mt,    // [4][256][KAUG]
                               _Float16* __restrict__ W1t)   // [256][64]
{
    const int t = threadIdx.x;          // 0..255
    const int b = blockIdx.x;
    if (b < 64) {
        const int l  = b >> 4;
        const int ng = b & 15;
        __shared__ float cosTab[256];
        __shared__ float cs[256];
        cosTab[t] = cosf((float)t * (6.28318530717958647692f / 256.0f));
        __syncthreads();
        // cs[t] = irfft(fw_l)[t]
        {
            const float* fwl = fw + l * 129;
            float s = fwl[0];
            #pragma unroll 4
            for (int k = 1; k < 128; ++k)
                s += 2.0f * fwl[k] * cosTab[(k * t) & 255];
            s += fwl[128] * ((t & 1) ? -1.0f : 1.0f);
            cs[t] = s * (1.0f / 256.0f);
        }
        __syncthreads();
        for (int idx = t; idx < 16 * KAUG; idx += 256) {
            const int n = ng * 16 + idx / KAUG;
            const int k = idx % KAUG;
            float v = 0.0f;
            if (k < 253)               v = cs[(n - k - 3) & 255];  // conv: h[k] -> d[k+3]
            if (k == n)                v += lw[l * 256 + n];       // diagonal residual lw
            if (k >= 256 && k < 259)   v = cs[(n - (k - 256)) & 255]; // x rows
            Mt[((size_t)l * 256 + n) * KAUG + k] = (_Float16)v;
        }
    } else {
        const int base = (b - 64) * 4096;
        #pragma unroll
        for (int i = 0; i < 16; ++i) {
            const int idx = base + t + i * 256;
            const int n = idx >> 6, k = idx & 63;
            W1t[idx] = (_Float16)W1[k * 256 + n];
        }
    }
}

// ---------------------------------------------------------------------------
// Fused main kernel, 32x32x16 MFMA. Block = 64 rows x 256 threads (4 waves);
// wave w owns feature stripe [64w, 64w+64) = 2 tiles of 32; rows = 2 tiles.
// LDS 39,936 B/block -> 4 blocks/CU (16 waves/CU) for latency hiding.
// mfma(Mt_frag, h_frag): D lane = h-row (lane&31), regs = 16 features.
// x-augmentation lives in hA cols 256..258 (cols 259..295 zero).
// ---------------------------------------------------------------------------
__global__ __launch_bounds__(256, 4)
void fno_main(const float* __restrict__ mu,
              const float* __restrict__ x,
              const float* __restrict__ b1,
              const float* __restrict__ W2,
              const float* __restrict__ b2,
              const _Float16* __restrict__ Mt,
              const _Float16* __restrict__ W1t,
              float* __restrict__ out)
{
    __shared__ __align__(16) _Float16 hA[BM * LDA];   // 37,888 B
    __shared__ float b1s[256];                        // encoder bias; reused as decoder red
    __shared__ float W2s[256];

    const int t    = threadIdx.x;
    const int w    = t >> 6;        // wave id: feature stripe 64*w
    const int lane = t & 63;
    const int i32  = lane & 31;     // Mt-frag feature / h-frag row / D h-row
    const int hi   = lane >> 5;     // k-half (inputs) / feature sub-offset (D)
    const int r0   = blockIdx.x * BM;

    // ---- stage mu -> hA cols 0..63 (fp16); zero aug cols 256..295 ----
    {
        const float4* mu4 = (const float4*)mu + (size_t)r0 * 16;  // 16 float4 per row
        #pragma unroll
        for (int j = 0; j < 4; ++j) {
            int f = t + 256 * j;              // [0, 1024)
            int row = f >> 4, c4 = f & 15;
            float4 v = mu4[f];
            f16x4 h;
            h[0] = (_Float16)v.x; h[1] = (_Float16)v.y;
            h[2] = (_Float16)v.z; h[3] = (_Float16)v.w;
            *(f16x4*)&hA[row * LDA + c4 * 4] = h;
        }
        f16x8 z8 = {(_Float16)0, (_Float16)0, (_Float16)0, (_Float16)0,
                    (_Float16)0, (_Float16)0, (_Float16)0, (_Float16)0};
        #pragma unroll
        for (int j = 0; j < 2; ++j) {
            int idx = t + 256 * j;            // [0, 320) : 64 rows x 5 groups
            if (idx < BM * 5) {
                int row = idx / 5, c = 256 + 8 * (idx % 5);
                *(f16x8*)&hA[row * LDA + c] = z8;
            }
        }
    }
    __syncthreads();   // aug region zeroed before x insert
    if (t < BM) {
        const float* xp = x + (size_t)(r0 + t) * 3;
        hA[t * LDA + 256] = (_Float16)xp[0];
        hA[t * LDA + 257] = (_Float16)xp[1];
        hA[t * LDA + 258] = (_Float16)xp[2];
    }
    b1s[t] = b1[t];
    W2s[t] = W2[t];
    __syncthreads();

    f32x16 acc[2][2];   // [feature-tile][row-tile], 64 regs

    // ================= encoder: h = relu(mu @ W1 + b1), K = 64 =================
    #pragma unroll
    for (int ft = 0; ft < 2; ++ft)
        #pragma unroll
        for (int rt = 0; rt < 2; ++rt)
            acc[ft][rt] = (f32x16)(0.f);

    #pragma unroll
    for (int ks = 0; ks < 4; ++ks) {
        const int kb = ks * 16;
        f16x8 mfrag[2];
        #pragma unroll
        for (int ft = 0; ft < 2; ++ft) {
            int n = 64 * w + 32 * ft + i32;
            mfrag[ft] = *(const f16x8*)(W1t + n * 64 + kb + 8 * hi);
        }
        #pragma unroll
        for (int rt = 0; rt < 2; ++rt) {
            f16x8 hfrag = *(const f16x8*)&hA[(32 * rt + i32) * LDA + kb + 8 * hi];
            #pragma unroll
            for (int ft = 0; ft < 2; ++ft)
                acc[ft][rt] = __builtin_amdgcn_mfma_f32_32x32x16_f16(
                    mfrag[ft], hfrag, acc[ft][rt], 0, 0, 0);
        }
    }
    __syncthreads();   // all reads of mu-region done before overwrite
    #pragma unroll
    for (int ft = 0; ft < 2; ++ft) {
        const int fb = 64 * w + 32 * ft + 4 * hi;
        #pragma unroll
        for (int rt = 0; rt < 2; ++rt) {
            const int row = 32 * rt + i32;
            #pragma unroll
            for (int g = 0; g < 4; ++g) {
                const float4 bias = *(const float4*)&b1s[fb + 8 * g];
                f16x4 hv;
                hv[0] = (_Float16)fmaxf(acc[ft][rt][4 * g + 0] + bias.x, 0.f);
                hv[1] = (_Float16)fmaxf(acc[ft][rt][4 * g + 1] + bias.y, 0.f);
                hv[2] = (_Float16)fmaxf(acc[ft][rt][4 * g + 2] + bias.z, 0.f);
                hv[3] = (_Float16)fmaxf(acc[ft][rt][4 * g + 3] + bias.w, 0.f);
                *(f16x4*)&hA[row * LDA + fb + 8 * g] = hv;
            }
        }
    }

    // ================= 4 Fourier layers: h = relu(h @ M_l + x @ X_l) ==========
    #pragma unroll 1
    for (int l = 0; l < 4; ++l) {
        __syncthreads();   // hA writes from previous stage visible
        #pragma unroll
        for (int ft = 0; ft < 2; ++ft)
            #pragma unroll
            for (int rt = 0; rt < 2; ++rt)
                acc[ft][rt] = (f32x16)(0.f);

        const _Float16* Ml = Mt + (size_t)l * 256 * KAUG;
        #pragma unroll
        for (int ks = 0; ks < 18; ++ks) {
            const int kb = ks * 16;
            f16x8 mfrag[2];
            #pragma unroll
            for (int ft = 0; ft < 2; ++ft) {
                int n = 64 * w + 32 * ft + i32;
                mfrag[ft] = *(const f16x8*)(Ml + n * KAUG + kb + 8 * hi);
            }
            #pragma unroll
            for (int rt = 0; rt < 2; ++rt) {
                f16x8 hfrag = *(const f16x8*)&hA[(32 * rt + i32) * LDA + kb + 8 * hi];
                #pragma unroll
                for (int ft = 0; ft < 2; ++ft)
                    acc[ft][rt] = __builtin_amdgcn_mfma_f32_32x32x16_f16(
                        mfrag[ft], hfrag, acc[ft][rt], 0, 0, 0);
            }
        }
        __syncthreads();   // all hA reads done before overwrite
        #pragma unroll
        for (int ft = 0; ft < 2; ++ft) {
            const int fb = 64 * w + 32 * ft + 4 * hi;
            #pragma unroll
            for (int rt = 0; rt < 2; ++rt) {
                const int row = 32 * rt + i32;
                #pragma unroll
                for (int g = 0; g < 4; ++g) {
                    f16x4 hv;
                    hv[0] = (_Float16)fmaxf(acc[ft][rt][4 * g + 0], 0.f);
                    hv[1] = (_Float16)fmaxf(acc[ft][rt][4 * g + 1], 0.f);
                    hv[2] = (_Float16)fmaxf(acc[ft][rt][4 * g + 2], 0.f);
                    hv[3] = (_Float16)fmaxf(acc[ft][rt][4 * g + 3], 0.f);
                    *(f16x4*)&hA[row * LDA + fb + 8 * g] = hv;
                }
            }
        }
    }

    // ================= decoder: out = h @ W2 + b2 =============================
    // wave w sums features [64w,64w+64) of row `lane`; cross-wave reduce in b1s.
    __syncthreads();
    {
        float* redS = b1s;    // b1s dead since encoder epilogue
        const int n0 = w * 64;
        float s = 0.f;
        #pragma unroll
        for (int j = 0; j < 8; ++j) {
            f16x8 v = *(const f16x8*)&hA[lane * LDA + n0 + 8 * j];
            const float* wp = &W2s[n0 + 8 * j];
            s += (float)v[0] * wp[0] + (float)v[1] * wp[1]
               + (float)v[2] * wp[2] + (float)v[3] * wp[3]
               + (float)v[4] * wp[4] + (float)v[5] * wp[5]
               + (float)v[6] * wp[6] + (float)v[7] * wp[7];
        }
        redS[t] = s;
        __syncthreads();
        if (t < BM)
            out[r0 + t] = redS[t] + redS[64 + t] + redS[128 + t] + redS[192 + t] + b2[0];
    }
}

// ---------------------------------------------------------------------------
extern "C" void kernel_launch(void* const* d_in, const int* in_sizes, int n_in,
                              void* d_out, int out_size, void* d_ws, size_t ws_size,
                              hipStream_t stream) {
    const float* mu = (const float*)d_in[0];
    const float* x  = (const float*)d_in[1];
    const float* W1 = (const float*)d_in[2];
    const float* b1 = (const float*)d_in[3];
    const float* fw = (const float*)d_in[4];
    const float* lw = (const float*)d_in[5];
    const float* W2 = (const float*)d_in[6];
    const float* b2 = (const float*)d_in[7];
    float* out = (float*)d_out;

    _Float16* Mt  = (_Float16*)d_ws;
    _Float16* W1t = Mt + 4 * 256 * KAUG;

    fno_precompute<<<68, 256, 0, stream>>>(W1, fw, lw, Mt, W1t);
    fno_main<<<N_B / BM, 256, 0, stream>>>(mu, x, b1, W2, b2, Mt, W1t, out);
}

// Round 6
// 262.197 us; speedup vs baseline: 1.3030x; 1.3030x over previous
//
#include <hip/hip_runtime.h>

#define N_B   262144
#define BM    256      // rows per block; 512 threads = 8 waves (4 fw x 2 rw)
#define KAUG  288      // 256 (h) + 32 (x-augmentation, only 3 used)
#define LDA   296      // hA row stride in halves

typedef _Float16 f16x8  __attribute__((ext_vector_type(8)));
typedef _Float16 f16x4  __attribute__((ext_vector_type(4)));
typedef float    f32x16 __attribute__((ext_vector_type(16)));

// ---------------------------------------------------------------------------
// Precompute (68 blocks, ~5 us):
//   blocks 0..63 : (l = b>>4, row-group ng = b&15) -> Mt[l][16ng..16ng+16)[*]
//   blocks 64..67: W1t[n][k] = W1[k][n] transpose.
// ---------------------------------------------------------------------------
__global__ void fno_precompute(const float* __restrict__ W1,
                               const float* __restrict__ fw,
                               const float* __restrict__ lw,
                               _Float16* __restrict__ Mt,    // [4][256][KAUG]
                               _Float16* __restrict__ W1t)   // [256][64]
{
    const int t = threadIdx.x;          // 0..255
    const int b = blockIdx.x;
    if (b < 64) {
        const int l  = b >> 4;
        const int ng = b & 15;
        __shared__ float cosTab[256];
        __shared__ float cs[256];
        cosTab[t] = cosf((float)t * (6.28318530717958647692f / 256.0f));
        __syncthreads();
        // cs[t] = irfft(fw_l)[t]
        {
            const float* fwl = fw + l * 129;
            float s = fwl[0];
            #pragma unroll 4
            for (int k = 1; k < 128; ++k)
                s += 2.0f * fwl[k] * cosTab[(k * t) & 255];
            s += fwl[128] * ((t & 1) ? -1.0f : 1.0f);
            cs[t] = s * (1.0f / 256.0f);
        }
        __syncthreads();
        for (int idx = t; idx < 16 * KAUG; idx += 256) {
            const int n = ng * 16 + idx / KAUG;
            const int k = idx % KAUG;
            float v = 0.0f;
            if (k < 253)               v = cs[(n - k - 3) & 255];  // conv: h[k] -> d[k+3]
            if (k == n)                v += lw[l * 256 + n];       // diagonal residual lw
            if (k >= 256 && k < 259)   v = cs[(n - (k - 256)) & 255]; // x rows
            Mt[((size_t)l * 256 + n) * KAUG + k] = (_Float16)v;
        }
    } else {
        const int base = (b - 64) * 4096;
        #pragma unroll
        for (int i = 0; i < 16; ++i) {
            const int idx = base + t + i * 256;
            const int n = idx >> 6, k = idx & 63;
            W1t[idx] = (_Float16)W1[k * 256 + n];
        }
    }
}

// ---------------------------------------------------------------------------
// Fused main kernel, 32x32x16 MFMA. Block = 256 rows x 512 threads (8 waves).
// Wave wid: fw = wid&3 -> feature stripe [64fw, 64fw+64) (2 ft-tiles);
//           rw = wid>>2 -> rows [128rw, 128rw+128) (4 rt-tiles).
// acc = 2x4x16 = 128 AGPRs; VGPR side has headroom for explicit depth-3
// rolling prefetch of the per-step Mt fragments (the round-4 diagnosis:
// zero-prefetch K-loops are L2-latency-bound).
// ---------------------------------------------------------------------------
__global__ __launch_bounds__(512, 2)
void fno_main(const float* __restrict__ mu,
              const float* __restrict__ x,
              const float* __restrict__ b1,
              const float* __restrict__ W2,
              const float* __restrict__ b2,
              const _Float16* __restrict__ Mt,
              const _Float16* __restrict__ W1t,
              float* __restrict__ out)
{
    __shared__ __align__(16) _Float16 hA[BM * LDA];   // 151,552 B
    __shared__ float b1s[256];
    __shared__ float W2s[256];

    const int t    = threadIdx.x;
    const int wid  = t >> 6;
    const int fw   = wid & 3;       // feature stripe 64*fw
    const int rw   = wid >> 2;      // row half 128*rw
    const int lane = t & 63;
    const int i32  = lane & 31;     // Mt-frag feature / h-frag row / D h-row
    const int hi   = lane >> 5;     // k-half (inputs) / feature sub-offset (D)
    const int r0   = blockIdx.x * BM;

    // ---- stage mu -> hA cols 0..63 (fp16); zero aug cols 256..295 ----
    {
        const float4* mu4 = (const float4*)mu + (size_t)r0 * 16;  // 16 float4 per row
        #pragma unroll
        for (int j = 0; j < 8; ++j) {
            int f = t + 512 * j;              // [0, 4096)
            int row = f >> 4, c4 = f & 15;
            float4 v = mu4[f];
            f16x4 h;
            h[0] = (_Float16)v.x; h[1] = (_Float16)v.y;
            h[2] = (_Float16)v.z; h[3] = (_Float16)v.w;
            *(f16x4*)&hA[row * LDA + c4 * 4] = h;
        }
        f16x8 z8 = {(_Float16)0, (_Float16)0, (_Float16)0, (_Float16)0,
                    (_Float16)0, (_Float16)0, (_Float16)0, (_Float16)0};
        #pragma unroll
        for (int j = 0; j < 3; ++j) {
            int idx = t + 512 * j;            // [0, 1280) : 256 rows x 5 groups
            if (idx < BM * 5) {
                int row = idx / 5, c = 256 + 8 * (idx % 5);
                *(f16x8*)&hA[row * LDA + c] = z8;
            }
        }
    }
    __syncthreads();   // aug region zeroed before x insert
    if (t < BM) {
        const float* xp = x + (size_t)(r0 + t) * 3;
        hA[t * LDA + 256] = (_Float16)xp[0];
        hA[t * LDA + 257] = (_Float16)xp[1];
        hA[t * LDA + 258] = (_Float16)xp[2];
    }
    if (t < 256) { b1s[t] = b1[t]; W2s[t] = W2[t]; }
    __syncthreads();

    f32x16 acc[2][4];   // [feature-tile][row-tile], 128 AGPRs

    // ================= encoder: h = relu(mu @ W1 + b1), K = 64 =================
    #pragma unroll
    for (int ft = 0; ft < 2; ++ft)
        #pragma unroll
        for (int rt = 0; rt < 4; ++rt)
            acc[ft][rt] = (f32x16)(0.f);

    {
        const _Float16* m0 = W1t + (size_t)(64 * fw + i32) * 64 + 8 * hi;
        const _Float16* m1 = m0 + 32 * 64;
        #pragma unroll
        for (int ks = 0; ks < 4; ++ks) {
            f16x8 a0 = *(const f16x8*)(m0 + 16 * ks);
            f16x8 a1 = *(const f16x8*)(m1 + 16 * ks);
            #pragma unroll
            for (int rt = 0; rt < 4; ++rt) {
                f16x8 hfrag = *(const f16x8*)&hA[(128 * rw + 32 * rt + i32) * LDA + 16 * ks + 8 * hi];
                acc[0][rt] = __builtin_amdgcn_mfma_f32_32x32x16_f16(a0, hfrag, acc[0][rt], 0, 0, 0);
                acc[1][rt] = __builtin_amdgcn_mfma_f32_32x32x16_f16(a1, hfrag, acc[1][rt], 0, 0, 0);
            }
        }
    }
    __syncthreads();   // all reads of mu-region done before overwrite
    #pragma unroll
    for (int ft = 0; ft < 2; ++ft) {
        const int fb = 64 * fw + 32 * ft + 4 * hi;
        #pragma unroll
        for (int rt = 0; rt < 4; ++rt) {
            const int row = 128 * rw + 32 * rt + i32;
            #pragma unroll
            for (int g = 0; g < 4; ++g) {
                const float4 bias = *(const float4*)&b1s[fb + 8 * g];
                f16x4 hv;
                hv[0] = (_Float16)fmaxf(acc[ft][rt][4 * g + 0] + bias.x, 0.f);
                hv[1] = (_Float16)fmaxf(acc[ft][rt][4 * g + 1] + bias.y, 0.f);
                hv[2] = (_Float16)fmaxf(acc[ft][rt][4 * g + 2] + bias.z, 0.f);
                hv[3] = (_Float16)fmaxf(acc[ft][rt][4 * g + 3] + bias.w, 0.f);
                *(f16x4*)&hA[row * LDA + fb + 8 * g] = hv;
            }
        }
    }

    // ================= 4 Fourier layers: h = relu(h @ M_l + x @ X_l) ==========
    #pragma unroll 1
    for (int l = 0; l < 4; ++l) {
        __syncthreads();   // hA writes from previous stage visible
        #pragma unroll
        for (int ft = 0; ft < 2; ++ft)
            #pragma unroll
            for (int rt = 0; rt < 4; ++rt)
                acc[ft][rt] = (f32x16)(0.f);

        const _Float16* Ml = Mt + (size_t)l * 256 * KAUG;
        const _Float16* m0 = Ml + (size_t)(64 * fw + i32) * KAUG + 8 * hi;
        const _Float16* m1 = m0 + 32 * KAUG;

        // depth-3 rolling prefetch of Mt fragments (L2-latency cover)
        f16x8 mf0[3], mf1[3];
        mf0[0] = *(const f16x8*)(m0);       mf1[0] = *(const f16x8*)(m1);
        mf0[1] = *(const f16x8*)(m0 + 16);  mf1[1] = *(const f16x8*)(m1 + 16);
        mf0[2] = *(const f16x8*)(m0 + 32);  mf1[2] = *(const f16x8*)(m1 + 32);

        #pragma unroll
        for (int ks = 0; ks < 18; ++ks) {
            const int cur = ks % 3;
            f16x8 a0 = mf0[cur], a1 = mf1[cur];
            if (ks < 15) {
                mf0[cur] = *(const f16x8*)(m0 + 16 * (ks + 3));
                mf1[cur] = *(const f16x8*)(m1 + 16 * (ks + 3));
            }
            #pragma unroll
            for (int rt = 0; rt < 4; ++rt) {
                f16x8 hfrag = *(const f16x8*)&hA[(128 * rw + 32 * rt + i32) * LDA + 16 * ks + 8 * hi];
                acc[0][rt] = __builtin_amdgcn_mfma_f32_32x32x16_f16(a0, hfrag, acc[0][rt], 0, 0, 0);
                acc[1][rt] = __builtin_amdgcn_mfma_f32_32x32x16_f16(a1, hfrag, acc[1][rt], 0, 0, 0);
            }
        }
        __syncthreads();   // all hA reads done before overwrite
        #pragma unroll
        for (int ft = 0; ft < 2; ++ft) {
            const int fb = 64 * fw + 32 * ft + 4 * hi;
            #pragma unroll
            for (int rt = 0; rt < 4; ++rt) {
                const int row = 128 * rw + 32 * rt + i32;
                #pragma unroll
                for (int g = 0; g < 4; ++g) {
                    f16x4 hv;
                    hv[0] = (_Float16)fmaxf(acc[ft][rt][4 * g + 0], 0.f);
                    hv[1] = (_Float16)fmaxf(acc[ft][rt][4 * g + 1], 0.f);
                    hv[2] = (_Float16)fmaxf(acc[ft][rt][4 * g + 2], 0.f);
                    hv[3] = (_Float16)fmaxf(acc[ft][rt][4 * g + 3], 0.f);
                    *(f16x4*)&hA[row * LDA + fb + 8 * g] = hv;
                }
            }
        }
    }

    // ================= decoder: out = h @ W2 + b2 =============================
    // 2 threads per row (half = t&1, 128 features each); pair-reduce via shfl.
    __syncthreads();
    {
        const int row  = t >> 1;
        const int half = t & 1;
        const int n0   = 128 * half;
        float s = 0.f;
        #pragma unroll
        for (int j = 0; j < 16; ++j) {
            f16x8 v = *(const f16x8*)&hA[row * LDA + n0 + 8 * j];
            const float* wp = &W2s[n0 + 8 * j];
            s += (float)v[0] * wp[0] + (float)v[1] * wp[1]
               + (float)v[2] * wp[2] + (float)v[3] * wp[3]
               + (float)v[4] * wp[4] + (float)v[5] * wp[5]
               + (float)v[6] * wp[6] + (float)v[7] * wp[7];
        }
        s += __shfl_xor(s, 1);
        if (!half) out[r0 + row] = s + b2[0];
    }
}

// ---------------------------------------------------------------------------
extern "C" void kernel_launch(void* const* d_in, const int* in_sizes, int n_in,
                              void* d_out, int out_size, void* d_ws, size_t ws_size,
                              hipStream_t stream) {
    const float* mu = (const float*)d_in[0];
    const float* x  = (const float*)d_in[1];
    const float* W1 = (const float*)d_in[2];
    const float* b1 = (const float*)d_in[3];
    const float* fw = (const float*)d_in[4];
    const float* lw = (const float*)d_in[5];
    const float* W2 = (const float*)d_in[6];
    const float* b2 = (const float*)d_in[7];
    float* out = (float*)d_out;

    _Float16* Mt  = (_Float16*)d_ws;
    _Float16* W1t = Mt + 4 * 256 * KAUG;

    fno_precompute<<<68, 256, 0, stream>>>(W1, fw, lw, Mt, W1t);
    fno_main<<<N_B / BM, 512, 0, stream>>>(mu, x, b1, W2, b2, Mt, W1t, out);
}

// Round 7
// 243.062 us; speedup vs baseline: 1.4055x; 1.0787x over previous
//
#include <hip/hip_runtime.h>

#define N_B   262144
#define BM    128      // rows per block, 256 threads = 4 waves (feature stripes)
#define LDA   264      // hA row stride in halves (528 B, 16B-aligned rows)

typedef _Float16 f16x8  __attribute__((ext_vector_type(8)));
typedef _Float16 f16x4  __attribute__((ext_vector_type(4)));
typedef float    f32x16 __attribute__((ext_vector_type(16)));

// ---------------------------------------------------------------------------
// Precompute (68 blocks):
//  blocks 0..63 : Mt[l][n][k] (l=b>>4, 16 rows each), K=256 circulant over the
//                 rotated state t=[h0..h252,x0,x1,x2], lw folded at k==n (n<=252).
//  blocks 64..67: W1t[n][k] = W1[k][n].
// ---------------------------------------------------------------------------
__global__ void fno_precompute(const float* __restrict__ W1,
                               const float* __restrict__ fw,
                               const float* __restrict__ lw,
                               _Float16* __restrict__ Mt,    // [4][256][256]
                               _Float16* __restrict__ W1t)   // [256][64]
{
    const int t = threadIdx.x;          // 0..255
    const int b = blockIdx.x;
    if (b < 64) {
        const int l  = b >> 4;
        const int ng = b & 15;
        __shared__ float cosTab[256];
        __shared__ float cs[256];
        cosTab[t] = cosf((float)t * (6.28318530717958647692f / 256.0f));
        __syncthreads();
        {
            const float* fwl = fw + l * 129;
            float s = fwl[0];
            #pragma unroll 4
            for (int k = 1; k < 128; ++k)
                s += 2.0f * fwl[k] * cosTab[(k * t) & 255];
            s += fwl[128] * ((t & 1) ? -1.0f : 1.0f);
            cs[t] = s * (1.0f / 256.0f);
        }
        __syncthreads();
        for (int idx = t; idx < 16 * 256; idx += 256) {
            const int n = ng * 16 + (idx >> 8);
            const int k = idx & 255;
            float v;
            if (k < 253) {
                v = cs[(n - k - 3) & 255];        // coeff of t[k]=h[k] (d[k+3])
                if (k == n) v += lw[l * 256 + n]; // aligned lw diagonal (n<=252)
            } else {
                v = cs[(n - (k - 253)) & 255];    // coeff of t[253+m]=x[m]
            }
            Mt[((size_t)l * 256 + n) * 256 + k] = (_Float16)v;
        }
    } else {
        const int base = (b - 64) * 4096;
        #pragma unroll
        for (int i = 0; i < 16; ++i) {
            const int idx = base + t + i * 256;
            const int n = idx >> 6, k = idx & 63;
            W1t[idx] = (_Float16)W1[k * 256 + n];
        }
    }
}

// ---------------------------------------------------------------------------
// Fused main kernel, 32x32x16 MFMA, K=256 rotated-state formulation.
// Block = 128 rows x 256 threads (4 waves); wave w owns features [64w,64w+64).
// State t in hA: t[0..252]=h[0..252], t[253..255]=x (persistent).
// h[253..255] tracked per-row in f32 side array hT (lw-chained).
// K-loop: explicit 1-step lookahead on the two Mt fragments (L2 latency).
// ---------------------------------------------------------------------------
__global__ __launch_bounds__(256, 2)
void fno_main(const float* __restrict__ mu,
              const float* __restrict__ x,
              const float* __restrict__ b1,
              const float* __restrict__ W2,
              const float* __restrict__ b2,
              const float* __restrict__ lw,
              const _Float16* __restrict__ Mt,
              const _Float16* __restrict__ W1t,
              float* __restrict__ out)
{
    __shared__ __align__(16) _Float16 hA[BM * LDA];   // 67,584 B
    __shared__ float b1s[256];                        // bias; reused as decoder red
    __shared__ float W2s[256];
    __shared__ float hT[BM][4];                       // h[253..255] per row (f32)

    const int t    = threadIdx.x;
    const int w    = t >> 6;        // wave id: feature stripe 64*w
    const int lane = t & 63;
    const int i32  = lane & 31;     // Mt-frag feature / h-frag row / D h-row
    const int hi   = lane >> 5;     // k-half (inputs) / feature sub-offset (D)
    const int r0   = blockIdx.x * BM;

    // ---- stage mu -> hA cols 0..63 ; x -> cols 253..255 ----
    {
        const float4* mu4 = (const float4*)mu + (size_t)r0 * 16;  // 16 float4/row
        #pragma unroll
        for (int j = 0; j < 8; ++j) {
            int f = t + 256 * j;              // [0, 2048)
            int row = f >> 4, c4 = f & 15;
            float4 v = mu4[f];
            f16x4 h;
            h[0] = (_Float16)v.x; h[1] = (_Float16)v.y;
            h[2] = (_Float16)v.z; h[3] = (_Float16)v.w;
            *(f16x4*)&hA[row * LDA + c4 * 4] = h;
        }
    }
    if (t < BM) {
        const float* xp = x + (size_t)(r0 + t) * 3;
        hA[t * LDA + 253] = (_Float16)xp[0];
        hA[t * LDA + 254] = (_Float16)xp[1];
        hA[t * LDA + 255] = (_Float16)xp[2];
    }
    b1s[t] = b1[t];
    W2s[t] = (t >= 253) ? 0.f : W2[t];
    __syncthreads();

    f32x16 acc[2][4];   // [feature-tile][row-tile], 128 AGPRs

    // ================= encoder: h = relu(mu @ W1 + b1), K = 64 =================
    #pragma unroll
    for (int ft = 0; ft < 2; ++ft)
        #pragma unroll
        for (int rt = 0; rt < 4; ++rt)
            acc[ft][rt] = (f32x16)(0.f);

    #pragma unroll
    for (int ks = 0; ks < 4; ++ks) {
        const int kb = ks * 16;
        f16x8 mfrag[2];
        #pragma unroll
        for (int ft = 0; ft < 2; ++ft) {
            int n = 64 * w + 32 * ft + i32;
            mfrag[ft] = *(const f16x8*)(W1t + n * 64 + kb + 8 * hi);
        }
        #pragma unroll
        for (int rt = 0; rt < 4; ++rt) {
            f16x8 hfrag = *(const f16x8*)&hA[(32 * rt + i32) * LDA + kb + 8 * hi];
            #pragma unroll
            for (int ft = 0; ft < 2; ++ft)
                acc[ft][rt] = __builtin_amdgcn_mfma_f32_32x32x16_f16(
                    mfrag[ft], hfrag, acc[ft][rt], 0, 0, 0);
        }
    }
    __syncthreads();   // all reads of mu-region done before overwrite
    #pragma unroll
    for (int ft = 0; ft < 2; ++ft) {
        const int fb = 64 * w + 32 * ft + 4 * hi;
        #pragma unroll
        for (int rt = 0; rt < 4; ++rt) {
            const int row = 32 * rt + i32;
            #pragma unroll
            for (int g = 0; g < 4; ++g) {
                const float4 bias = *(const float4*)&b1s[fb + 8 * g];
                float v0 = fmaxf(acc[ft][rt][4 * g + 0] + bias.x, 0.f);
                float v1 = fmaxf(acc[ft][rt][4 * g + 1] + bias.y, 0.f);
                float v2 = fmaxf(acc[ft][rt][4 * g + 2] + bias.z, 0.f);
                float v3 = fmaxf(acc[ft][rt][4 * g + 3] + bias.w, 0.f);
                if (w == 3 && ft == 1 && hi == 1 && g == 3) {
                    // features 252..255: t[252] = h252; hT = h[253..255]
                    hA[row * LDA + 252] = (_Float16)v0;
                    hT[row][0] = v1; hT[row][1] = v2; hT[row][2] = v3;
                } else {
                    f16x4 hv;
                    hv[0] = (_Float16)v0; hv[1] = (_Float16)v1;
                    hv[2] = (_Float16)v2; hv[3] = (_Float16)v3;
                    *(f16x4*)&hA[row * LDA + fb + 8 * g] = hv;
                }
            }
        }
    }

    // ================= 4 Fourier layers =================
    #pragma unroll 1
    for (int l = 0; l < 4; ++l) {
        __syncthreads();   // state writes visible
        #pragma unroll
        for (int ft = 0; ft < 2; ++ft)
            #pragma unroll
            for (int rt = 0; rt < 4; ++rt)
                acc[ft][rt] = (f32x16)(0.f);

        const _Float16* Ml = Mt + (size_t)l * 65536;
        const _Float16* m0 = Ml + (size_t)(64 * w + i32) * 256 + 8 * hi;
        const _Float16* m1 = m0 + 32 * 256;
        const float lw253 = lw[l * 256 + 253];
        const float lw254 = lw[l * 256 + 254];
        const float lw255 = lw[l * 256 + 255];

        f16x8 a0 = *(const f16x8*)m0;
        f16x8 a1 = *(const f16x8*)m1;
        #pragma unroll
        for (int ks = 0; ks < 16; ++ks) {
            f16x8 n0, n1;
            if (ks < 15) {                      // 1-step lookahead (L2 latency)
                n0 = *(const f16x8*)(m0 + 16 * (ks + 1));
                n1 = *(const f16x8*)(m1 + 16 * (ks + 1));
            }
            #pragma unroll
            for (int rt = 0; rt < 4; ++rt) {
                f16x8 hfrag = *(const f16x8*)&hA[(32 * rt + i32) * LDA + 16 * ks + 8 * hi];
                acc[0][rt] = __builtin_amdgcn_mfma_f32_32x32x16_f16(a0, hfrag, acc[0][rt], 0, 0, 0);
                acc[1][rt] = __builtin_amdgcn_mfma_f32_32x32x16_f16(a1, hfrag, acc[1][rt], 0, 0, 0);
            }
            if (ks < 15) { a0 = n0; a1 = n1; }
        }
        __syncthreads();   // all state reads done before overwrite
        #pragma unroll
        for (int ft = 0; ft < 2; ++ft) {
            const int fb = 64 * w + 32 * ft + 4 * hi;
            #pragma unroll
            for (int rt = 0; rt < 4; ++rt) {
                const int row = 32 * rt + i32;
                #pragma unroll
                for (int g = 0; g < 4; ++g) {
                    if (w == 3 && ft == 1 && hi == 1 && g == 3) {
                        // features 252..255 (lw for 253..255 NOT folded in Mt)
                        hA[row * LDA + 252] = (_Float16)fmaxf(acc[1][rt][12], 0.f);
                        float p0 = hT[row][0], p1 = hT[row][1], p2 = hT[row][2];
                        hT[row][0] = fmaxf(acc[1][rt][13] + lw253 * p0, 0.f);
                        hT[row][1] = fmaxf(acc[1][rt][14] + lw254 * p1, 0.f);
                        hT[row][2] = fmaxf(acc[1][rt][15] + lw255 * p2, 0.f);
                    } else {
                        f16x4 hv;
                        hv[0] = (_Float16)fmaxf(acc[ft][rt][4 * g + 0], 0.f);
                        hv[1] = (_Float16)fmaxf(acc[ft][rt][4 * g + 1], 0.f);
                        hv[2] = (_Float16)fmaxf(acc[ft][rt][4 * g + 2], 0.f);
                        hv[3] = (_Float16)fmaxf(acc[ft][rt][4 * g + 3], 0.f);
                        *(f16x4*)&hA[row * LDA + fb + 8 * g] = hv;
                    }
                }
            }
        }
    }

    // ================= decoder: out = h @ W2 + b2 =============================
    __syncthreads();
    {
        float* redS = b1s;                 // b1s dead since encoder epilogue
        const int r  = t & 127;
        const int hf = t >> 7;             // two threads per row
        const int n0 = hf * 128;
        float s = 0.f;
        #pragma unroll
        for (int j = 0; j < 16; ++j) {
            f16x8 v = *(const f16x8*)&hA[r * LDA + n0 + 8 * j];
            const float* wp = &W2s[n0 + 8 * j];
            s += (float)v[0] * wp[0] + (float)v[1] * wp[1]
               + (float)v[2] * wp[2] + (float)v[3] * wp[3]
               + (float)v[4] * wp[4] + (float)v[5] * wp[5]
               + (float)v[6] * wp[6] + (float)v[7] * wp[7];
        }
        if (hf == 0)
            s += hT[r][0] * W2[253] + hT[r][1] * W2[254] + hT[r][2] * W2[255];
        redS[t] = s;
        __syncthreads();
        if (t < BM)
            out[r0 + t] = redS[t] + redS[128 + t] + b2[0];
    }
}

// ---------------------------------------------------------------------------
extern "C" void kernel_launch(void* const* d_in, const int* in_sizes, int n_in,
                              void* d_out, int out_size, void* d_ws, size_t ws_size,
                              hipStream_t stream) {
    const float* mu = (const float*)d_in[0];
    const float* x  = (const float*)d_in[1];
    const float* W1 = (const float*)d_in[2];
    const float* b1 = (const float*)d_in[3];
    const float* fw = (const float*)d_in[4];
    const float* lw = (const float*)d_in[5];
    const float* W2 = (const float*)d_in[6];
    const float* b2 = (const float*)d_in[7];
    float* out = (float*)d_out;

    // workspace: Mt [4][256][256] f16 (524,288 B) + W1t [256][64] f16 (32 KB)
    _Float16* Mt  = (_Float16*)d_ws;
    _Float16* W1t = Mt + 4 * 256 * 256;

    fno_precompute<<<68, 256, 0, stream>>>(W1, fw, lw, Mt, W1t);
    fno_main<<<N_B / BM, 256, 0, stream>>>(mu, x, b1, W2, b2, lw, Mt, W1t, out);
}